// Round 1
// 140.329 us; speedup vs baseline: 1.0185x; 1.0185x over previous
//
#include <hip/hip_runtime.h>

// VectorQuantizer gather: out[b][d][n] = embedding[indices[b][n]][d]
// B=32, N=4096 (64x64), K=1024, D=256. fp32 out = 128 MiB -> write-BW bound.
//
// v2 design (LDS-transpose):
//  Previous kernel's wave-loads hit 64 distinct cache lines per instr (16B
//  used per 128B line) -> L2 request-rate bound (~61 us vs 21 us write floor).
//  Now:
//   - Block = (b, 64-wide n-tile); D processed in two 128-float halves.
//   - STAGE: 8-lane groups read 128B contiguous row segments (full-line
//     consumption; each wave-load = 2 rows x 512B contiguous). Exactly one
//     L2 line request per 128B of embedding data consumed.
//   - LDS tile [64][129] f32 (+1 pad): stage writes 4 scalars (4-way bank,
//     1.58x, cheap), store-phase column reads land 2-way per bank = free.
//   - STORE: float4 along n (16B/lane, 256B contiguous per 16-lane group),
//     4x fewer store instructions than the dword version.
//   - h=1 scattered loads issued BEFORE h=0 store phase (issue-early /
//     write-late) so read latency hides under the write stream.
//  LDS 33.3 KB -> 4 blocks/CU (16 waves). Grid 2048 x 256.

#define VQ_B 32
#define VQ_N 4096
#define VQ_D 256
#define TILE_N 64
#define HALF_D 128            // floats of d per pass
#define LDS_STRIDE 129        // +1 pad: column reads 2-way (free)

__global__ __launch_bounds__(256, 4) void vq_gather_kernel(
    const int* __restrict__ indices,
    const float* __restrict__ embedding,
    float* __restrict__ out)
{
    __shared__ int   s_idx[TILE_N];
    __shared__ float s_tile[TILE_N * LDS_STRIDE];

    const int bid = blockIdx.x;
    const int b   = bid >> 6;           // 0..31
    const int n0  = (bid & 63) << 6;    // n-tile base
    const int t   = threadIdx.x;

    if (t < TILE_N) s_idx[t] = indices[b * VQ_N + n0 + t];
    __syncthreads();

    // stage mapping: line-load id L = j*32 + g; row r = L>>2, 128B seg = L&3.
    // 8 lanes (s=0..7) cover one 128B segment -> full-line consumption.
    const int g = t >> 3;               // 0..31
    const int s = t & 7;                // 0..7

    // store mapping: lane group of 16 covers one d (256B contiguous along n)
    const int nl = t & 15;              // n = 4*nl .. 4*nl+3
    const int dg = t >> 4;              // 0..15

    float4 v0[8], v1[8];

    // ---- stage loads, half 0 (d 0..127) ----
    #pragma unroll
    for (int j = 0; j < 8; ++j) {
        const int L = j * 32 + g;
        const int r = L >> 2;
        const int c = (L & 3) * 8 + s;  // float4 index within half-row
        v0[j] = ((const float4*)(embedding + s_idx[r] * VQ_D))[c];
    }
    #pragma unroll
    for (int j = 0; j < 8; ++j) {
        const int L = j * 32 + g;
        const int r = L >> 2;
        const int c = (L & 3) * 8 + s;
        const float4 v = v0[j];
        float* p = &s_tile[r * LDS_STRIDE + c * 4];
        p[0] = v.x; p[1] = v.y; p[2] = v.z; p[3] = v.w;
    }
    __syncthreads();

    // ---- issue half-1 scattered loads now; latency hides under h0 stores ----
    #pragma unroll
    for (int j = 0; j < 8; ++j) {
        const int L = j * 32 + g;
        const int r = L >> 2;
        const int c = (L & 3) * 8 + s;
        v1[j] = ((const float4*)(embedding + s_idx[r] * VQ_D + HALF_D))[c];
    }

    // ---- store half 0: float4 along n ----
    #pragma unroll
    for (int jj = 0; jj < 8; ++jj) {
        const int d = jj * 16 + dg;     // 0..127
        float4 o;
        o.x = s_tile[(4 * nl + 0) * LDS_STRIDE + d];
        o.y = s_tile[(4 * nl + 1) * LDS_STRIDE + d];
        o.z = s_tile[(4 * nl + 2) * LDS_STRIDE + d];
        o.w = s_tile[(4 * nl + 3) * LDS_STRIDE + d];
        *(float4*)(out + (b * VQ_D + d) * VQ_N + n0 + 4 * nl) = o;
    }
    __syncthreads();

    // ---- write half-1 tile to LDS ----
    #pragma unroll
    for (int j = 0; j < 8; ++j) {
        const int L = j * 32 + g;
        const int r = L >> 2;
        const int c = (L & 3) * 8 + s;
        const float4 v = v1[j];
        float* p = &s_tile[r * LDS_STRIDE + c * 4];
        p[0] = v.x; p[1] = v.y; p[2] = v.z; p[3] = v.w;
    }
    __syncthreads();

    // ---- store half 1 ----
    #pragma unroll
    for (int jj = 0; jj < 8; ++jj) {
        const int d = jj * 16 + dg;
        float4 o;
        o.x = s_tile[(4 * nl + 0) * LDS_STRIDE + d];
        o.y = s_tile[(4 * nl + 1) * LDS_STRIDE + d];
        o.z = s_tile[(4 * nl + 2) * LDS_STRIDE + d];
        o.w = s_tile[(4 * nl + 3) * LDS_STRIDE + d];
        *(float4*)(out + (b * VQ_D + HALF_D + d) * VQ_N + n0 + 4 * nl) = o;
    }
}

extern "C" void kernel_launch(void* const* d_in, const int* in_sizes, int n_in,
                              void* d_out, int out_size, void* d_ws, size_t ws_size,
                              hipStream_t stream) {
    const int*   indices   = (const int*)d_in[0];    // (32,1,4096) int32
    const float* embedding = (const float*)d_in[1];  // (1024,256) fp32
    float* out = (float*)d_out;                      // (32,256,64,64) fp32

    vq_gather_kernel<<<dim3(VQ_B * (VQ_N / TILE_N)), dim3(256), 0, stream>>>(
        indices, embedding, out);
}